// Round 4
// baseline (156.961 us; speedup 1.0000x reference)
//
#include <hip/hip_runtime.h>
#include <hip/hip_bf16.h>

#define EPS 1e-6f

typedef __attribute__((ext_vector_type(8))) __bf16 bf16x8;
typedef __attribute__((ext_vector_type(4))) float f32x4;

// ---------------------------------------------------------------------------
// Fully fused yat-similarity kernel.
// One 256x256 block per output tile; reads f32 x/p directly, converts to
// bf16 (RTNE) during reg-staging into the swizzled LDS layout, computes
// row sums-of-squares on the fly (no split kernels, no workspace).
// Schedule: 4 phases per K-tile; loads for tile kt+1 issued ph1, cvt+write
// ph3 (A) / ph4 (B), lgkmcnt(0) drain before the publishing barrier.
// out = dots^2 / (xsq + psq - 2*dots + eps)
// ---------------------------------------------------------------------------
__global__ __launch_bounds__(512, 2) void yat_fused(
    const float* __restrict__ X, const float* __restrict__ Pr,
    float* __restrict__ out, int M, int N, int K) {

    __shared__ __align__(128) char sm[131072];   // 2 slots x (A 32KB + B 32KB)
    __shared__ float sqx[256];
    __shared__ float sqp[256];
    const char* smc = (const char*)sm;

    const int t = threadIdx.x;
    const int lane = t & 63;
    const int wid = t >> 6;        // 0..7
    const int wm = wid >> 2;       // 0..1  (row half of block)
    const int wn = wid & 3;        // 0..3  (col quarter of block)

    // T1: bijective XCD swizzle (total % 8 == 0 guaranteed by launch guard)
    const int nbx = N >> 8;
    const int nby = M >> 8;
    const int total = nbx * nby;
    int bid = blockIdx.x;
    bid = (bid & 7) * (total >> 3) + (bid >> 3);
    const int by = bid / nbx;
    const int bx = bid - by * nbx;
    const int brow = by << 8;
    const int bcol = bx << 8;

    const int NKT = K >> 6;         // K-tiles (16)

    f32x4 acc[8][4];
#pragma unroll
    for (int i = 0; i < 8; ++i)
#pragma unroll
        for (int j = 0; j < 4; ++j) acc[i][j] = (f32x4){0.f, 0.f, 0.f, 0.f};

    const int arow = lane & 15;           // fragment row/col within 16
    const int kq16 = (lane >> 4) * 16;    // byte offset of k-slot within 32-k half

    // ---- staging geometry (same LDS layout as the gload_lds version) ----
    // Thread (wid,lane,l) owns row rl = (l*8+wid)*8 + (lane>>3) of a 128-row
    // half-tile, physical col16 = lane&7; logical col16 lc = (lane&7)^(rl&7)
    // = (lane&7)^(lane>>3). It loads 8 f32 (k = lc*8..lc*8+7 of the 64-k
    // tile), converts to bf16, writes 16B at physical lane*16.
    const int rsub = lane >> 3;
    const int lc = (lane & 7) ^ rsub;
    int offA[2][2], offB[2][2];    // f32-element offsets into X / Pr
    int dofA[2][2], dofB[2][2];    // LDS byte offsets (sans slot)
#pragma unroll
    for (int hh = 0; hh < 2; ++hh)
#pragma unroll
        for (int l = 0; l < 2; ++l) {
            int rl = (l * 8 + wid) * 8 + rsub;
            offA[hh][l] = (brow + hh * 128 + rl) * K + lc * 8;
            offB[hh][l] = (bcol + hh * 128 + rl) * K + lc * 8;
            dofA[hh][l] = hh * 16384 + (l * 8 + wid) * 1024 + lane * 16;
            dofB[hh][l] = 32768 + hh * 16384 + (l * 8 + wid) * 1024 + lane * 16;
        }

    f32x4 sA[2][2][2], sB[2][2][2];               // in-flight f32 staging
    float qA[2][2] = {{0.f, 0.f}, {0.f, 0.f}};    // sum-of-squares accums
    float qB[2][2] = {{0.f, 0.f}, {0.f, 0.f}};

#define ISSUE(kt1) do {                                                        \
    _Pragma("unroll")                                                          \
    for (int hh_ = 0; hh_ < 2; ++hh_)                                          \
        _Pragma("unroll")                                                      \
        for (int l_ = 0; l_ < 2; ++l_) {                                       \
            sA[hh_][l_][0] = *(const f32x4*)(X + offA[hh_][l_] + (kt1) * 64);  \
            sA[hh_][l_][1] = *(const f32x4*)(X + offA[hh_][l_] + (kt1) * 64 + 4);\
            sB[hh_][l_][0] = *(const f32x4*)(Pr + offB[hh_][l_] + (kt1) * 64); \
            sB[hh_][l_][1] = *(const f32x4*)(Pr + offB[hh_][l_] + (kt1) * 64 + 4);\
        }                                                                      \
} while (0)

#define CVTWRITE(slot, S, Q, DOF) do {                                         \
    _Pragma("unroll")                                                          \
    for (int hh_ = 0; hh_ < 2; ++hh_)                                          \
        _Pragma("unroll")                                                      \
        for (int l_ = 0; l_ < 2; ++l_) {                                       \
            f32x4 u_ = S[hh_][l_][0], v_ = S[hh_][l_][1];                      \
            Q[hh_][l_] += u_[0]*u_[0] + u_[1]*u_[1] + u_[2]*u_[2] + u_[3]*u_[3]\
                        + v_[0]*v_[0] + v_[1]*v_[1] + v_[2]*v_[2] + v_[3]*v_[3];\
            bf16x8 pk_;                                                        \
            _Pragma("unroll")                                                  \
            for (int i_ = 0; i_ < 4; ++i_) {                                   \
                pk_[i_]     = (__bf16)u_[i_];                                  \
                pk_[4 + i_] = (__bf16)v_[i_];                                  \
            }                                                                  \
            *(bf16x8*)((char*)sm + (slot) * 65536 + DOF[hh_][l_]) = pk_;       \
        }                                                                      \
} while (0)

#define READ_A(slot, mh) do {                                                  \
    _Pragma("unroll")                                                          \
    for (int mi_ = 0; mi_ < 4; ++mi_) {                                        \
        int r_ = wm * 128 + (mh) * 64 + mi_ * 16 + arow;                       \
        const char* p_ = smc + (slot) * 65536 + r_ * 128;                      \
        int s_ = (r_ & 7) << 4;                                                \
        af[mi_][0] = *(const bf16x8*)(p_ + (kq16 ^ s_));                       \
        af[mi_][1] = *(const bf16x8*)(p_ + ((64 + kq16) ^ s_));                \
    }                                                                          \
} while (0)

#define READ_B(slot, nh, dst) do {                                             \
    _Pragma("unroll")                                                          \
    for (int ni_ = 0; ni_ < 2; ++ni_) {                                        \
        int r_ = wn * 64 + (nh) * 32 + ni_ * 16 + arow;                        \
        const char* p_ = smc + (slot) * 65536 + 32768 + r_ * 128;              \
        int s_ = (r_ & 7) << 4;                                                \
        dst[ni_][0] = *(const bf16x8*)(p_ + (kq16 ^ s_));                      \
        dst[ni_][1] = *(const bf16x8*)(p_ + ((64 + kq16) ^ s_));               \
    }                                                                          \
} while (0)

#define MFMA_Q(mh, nh, bset) do {                                              \
    __builtin_amdgcn_s_setprio(1);                                             \
    _Pragma("unroll")                                                          \
    for (int kk_ = 0; kk_ < 2; ++kk_)                                          \
        _Pragma("unroll")                                                      \
        for (int mi_ = 0; mi_ < 4; ++mi_)                                      \
            _Pragma("unroll")                                                  \
            for (int ni_ = 0; ni_ < 2; ++ni_)                                  \
                acc[(mh) * 4 + mi_][(nh) * 2 + ni_] =                          \
                    __builtin_amdgcn_mfma_f32_16x16x32_bf16(                   \
                        af[mi_][kk_], bset[ni_][kk_],                          \
                        acc[(mh) * 4 + mi_][(nh) * 2 + ni_], 0, 0, 0);         \
    __builtin_amdgcn_s_setprio(0);                                             \
} while (0)

#define PBAR() do {                                                            \
    __builtin_amdgcn_s_barrier();                                              \
    __builtin_amdgcn_sched_barrier(0);                                         \
    asm volatile("" ::: "memory");                                             \
} while (0)
#define LGKMDRAIN() asm volatile("s_waitcnt lgkmcnt(0)" ::: "memory")

    bf16x8 af[4][2];              // current A-half frags (overwritten ph3)
    bf16x8 bf0[2][2], bf1[2][2];  // B-quarter frags, live across the tile

    // prologue: stage tile 0 (load+cvt+write), drain, barrier.
    ISSUE(0);
    CVTWRITE(0, sA, qA, dofA);
    CVTWRITE(0, sB, qB, dofB);
    LGKMDRAIN();
    PBAR();

    for (int kt = 0; kt < NKT; ++kt) {
        const int slot = kt & 1;
        const bool more = (kt + 1) < NKT;

        // ph1: issue next-tile loads; read+MFMA Q00
        if (more) ISSUE(kt + 1);
        READ_A(slot, 0); READ_B(slot, 0, bf0);
        MFMA_Q(0, 0, bf0); PBAR();
        // ph2: read+MFMA Q01
        READ_B(slot, 1, bf1);
        MFMA_Q(0, 1, bf1); PBAR();
        // ph3: cvt+write next-tile A; read+MFMA Q10
        if (more) CVTWRITE(slot ^ 1, sA, qA, dofA);
        READ_A(slot, 1);
        MFMA_Q(1, 0, bf0); PBAR();
        // ph4: cvt+write next-tile B; MFMA Q11; drain; publish barrier
        if (more) CVTWRITE(slot ^ 1, sB, qB, dofB);
        MFMA_Q(1, 1, bf1);
        LGKMDRAIN();
        PBAR();
    }

#undef ISSUE
#undef CVTWRITE
#undef READ_A
#undef READ_B
#undef MFMA_Q
#undef PBAR
#undef LGKMDRAIN

    // ---- reduce per-thread sum-of-squares into sqx/sqp (local rows) ----
    // Each 8-lane group (same lane>>3) covers all 8 col16 slices of one row.
#pragma unroll
    for (int hh = 0; hh < 2; ++hh)
#pragma unroll
        for (int l = 0; l < 2; ++l) {
            float a = qA[hh][l], b = qB[hh][l];
#pragma unroll
            for (int m = 1; m <= 4; m <<= 1) {
                a += __shfl_xor(a, m);
                b += __shfl_xor(b, m);
            }
            if ((lane & 7) == 0) {
                int r = hh * 128 + l * 64 + wid * 8 + rsub;
                sqx[r] = a;
                sqp[r] = b;
            }
        }

    // epilogue: score = d^2 / (xsq + psq - 2d + eps), staged through LDS so
    // global stores are full 1KB-per-wave dwordx4 rows. Two passes of 128
    // rows (wm half each). Swizzle: logical (row,col) at physical
    // col ^ (((row>>2)&1)<<4); reader loads physical (lane*4)^swz (logical
    // cols [lane*4,+3]) and stores to bcol + lane*4.
    float* smf = (float*)sm;
#pragma unroll
    for (int pass = 0; pass < 2; ++pass) {
        __syncthreads();
        if (wm == pass) {
#pragma unroll
            for (int ni = 0; ni < 4; ++ni) {
                int lcc = wn * 64 + ni * 16 + arow;
                float ps = sqp[lcc];
#pragma unroll
                for (int mi = 0; mi < 8; ++mi) {
                    f32x4 c = acc[mi][ni];
                    int lr0 = mi * 16 + (lane >> 4) * 4;   // local row, mult of 4
                    f32x4 xs4 = *(const f32x4*)(&sqx[pass * 128 + lr0]);
                    int lcs = lcc ^ (((lr0 >> 2) & 1) << 4);
#pragma unroll
                    for (int j = 0; j < 4; ++j) {
                        float dv = c[j];
                        float denom = xs4[j] + ps - 2.0f * dv + EPS;
                        smf[(lr0 + j) * 256 + lcs] = dv * dv / denom;
                    }
                }
            }
        }
        __syncthreads();
#pragma unroll
        for (int rr = 0; rr < 16; ++rr) {
            int r = wid * 16 + rr;
            int swz = ((r >> 2) & 1) << 4;
            int c0 = lane * 4;                              // logical col
            f32x4 v = *(const f32x4*)(smf + r * 256 + (c0 ^ swz));
            *(f32x4*)(out + (size_t)(brow + pass * 128 + r) * N + bcol + c0) = v;
        }
    }
}

__global__ void yat_fallback(const float* __restrict__ x, const float* __restrict__ p,
                             float* __restrict__ out, int B, int P, int D) {
    __shared__ float xs[1024];
    int b = blockIdx.x;
    int pc = blockIdx.y * 256 + threadIdx.x;
    for (int i = threadIdx.x; i < D; i += 256) xs[i] = x[(size_t)b * D + i];
    __syncthreads();
    if (pc >= P) return;
    float dot = 0.f, psq = 0.f, xsq = 0.f;
    for (int k = 0; k < D; ++k) {
        float pv = p[(size_t)pc * D + k];
        float xv = xs[k];
        dot += xv * pv;
        psq += pv * pv;
        xsq += xv * xv;
    }
    float denom = xsq + psq - 2.f * dot + EPS;
    out[(size_t)b * P + pc] = dot * dot / denom;
}

extern "C" void kernel_launch(void* const* d_in, const int* in_sizes, int n_in,
                              void* d_out, int out_size, void* d_ws, size_t ws_size,
                              hipStream_t stream) {
    const float* x = (const float*)d_in[0];
    const float* p = (const float*)d_in[1];
    float* out = (float*)d_out;

    const int D = 1024;
    const int B = in_sizes[0] / D;
    const int P = in_sizes[1] / D;

    int nblocks = (B / 256) * (P / 256);
    if ((B % 256) || (P % 256) || (D % 64) || (nblocks % 8)) {
        yat_fallback<<<dim3(B, (P + 255) / 256), 256, 0, stream>>>(x, p, out, B, P, D);
        return;
    }

    yat_fused<<<dim3(nblocks), 512, 0, stream>>>(x, p, out, B, P, D);
}

// Round 5
// 61.733 us; speedup vs baseline: 2.5426x; 2.5426x over previous
//
#include <hip/hip_runtime.h>
#include <hip/hip_bf16.h>

#define EPS 1e-6f

typedef __attribute__((ext_vector_type(8))) __bf16 bf16x8;
typedef __attribute__((ext_vector_type(4))) float f32x4;

// ---------------------------------------------------------------------------
// Fully fused yat-similarity kernel, register-budgeted.
// 256x256 tile, 512 threads, 16x16x32 bf16 MFMA, swizzled LDS.
// f32 inputs are reg-staged in 4 chunks/tile (2 static 16-reg ping-pong
// buffers), converted to bf16 RTNE + sum-of-squares at write time.
// Chunk c issued one phase before its cvt+ds_write: peak staging = 32 VGPR.
// B fragments re-read from LDS each phase (single 16-reg buffer).
// out = dots^2 / (xsq + psq - 2*dots + eps)
// ---------------------------------------------------------------------------
__global__ __launch_bounds__(512, 2) void yat_fused(
    const float* __restrict__ X, const float* __restrict__ Pr,
    float* __restrict__ out, int M, int N, int K) {

    __shared__ __align__(128) char sm[131072];   // 2 slots x (A 32KB + B 32KB)
    __shared__ __align__(16) float sqx[256];
    __shared__ __align__(16) float sqp[256];
    const char* smc = (const char*)sm;

    const int t = threadIdx.x;
    const int lane = t & 63;
    const int wid = t >> 6;        // 0..7
    const int wm = wid >> 2;       // 0..1  (row half of block)
    const int wn = wid & 3;        // 0..3  (col quarter of block)

    // T1: bijective XCD swizzle (total % 8 == 0 guaranteed by launch guard)
    const int nbx = N >> 8;
    const int nby = M >> 8;
    const int total = nbx * nby;
    int bid = blockIdx.x;
    bid = (bid & 7) * (total >> 3) + (bid >> 3);
    const int by = bid / nbx;
    const int bx = bid - by * nbx;
    const int brow = by << 8;
    const int bcol = bx << 8;

    const int NKT = K >> 6;         // K-tiles (16)

    f32x4 acc[8][4];
#pragma unroll
    for (int i = 0; i < 8; ++i)
#pragma unroll
        for (int j = 0; j < 4; ++j) acc[i][j] = (f32x4){0.f, 0.f, 0.f, 0.f};

    const int arow = lane & 15;           // fragment row/col within 16
    const int kq16 = (lane >> 4) * 16;    // byte offset of k-slot within 32-k half

    // ---- staging geometry ----
    // Thread (wid,lane) + (hh,l) owns row rl = l*64 + wid*8 + (lane>>3) of
    // half-tile hh, logical col16 lc = (lane&7)^(lane>>3) (pre-swizzled so
    // the LDS image lands at physical col16 = lane&7, i.e. byte lane*16).
    const int rsub = lane >> 3;
    const int lcq = (lane & 7) ^ rsub;
    // element offsets: base + hh*128*K + l*64*K + kt*64
    const long baseA = (long)(brow + wid * 8 + rsub) * K + lcq * 8;
    const long baseB = (long)(bcol + wid * 8 + rsub) * K + lcq * 8;
    const long sH = (long)128 * K, sL = (long)64 * K;  // uniform (SGPR)
    // LDS byte offsets: dlane + hh*16384 + l*8192 (+32768 for B)
    const int dlane = wid * 1024 + lane * 16;

    f32x4 c0[4], c1[4];                           // ping-pong chunk buffers
    float qA[2][2] = {{0.f, 0.f}, {0.f, 0.f}};    // sum-of-squares accums
    float qB[2][2] = {{0.f, 0.f}, {0.f, 0.f}};

    // issue chunk: 4 f32x4 = rows (hh, l=0/1) of one matrix, k-tile kt
#define ISSUE(buf, G, BASE, hh, kt) do {                                       \
    const float* g0_ = (G) + BASE + (hh) * sH + (long)(kt) * 64;               \
    buf[0] = *(const f32x4*)(g0_);                                             \
    buf[1] = *(const f32x4*)(g0_ + 4);                                         \
    buf[2] = *(const f32x4*)(g0_ + sL);                                        \
    buf[3] = *(const f32x4*)(g0_ + sL + 4);                                    \
} while (0)

    // cvt + sumsq + ds_write chunk into slot (boff = 0 for A, 32768 for B)
#define WRITE(buf, Q, hh, slot, boff) do {                                     \
    _Pragma("unroll")                                                          \
    for (int l_ = 0; l_ < 2; ++l_) {                                           \
        f32x4 u_ = buf[2 * l_], v_ = buf[2 * l_ + 1];                          \
        Q[hh][l_] += u_[0]*u_[0] + u_[1]*u_[1] + u_[2]*u_[2] + u_[3]*u_[3]     \
                   + v_[0]*v_[0] + v_[1]*v_[1] + v_[2]*v_[2] + v_[3]*v_[3];    \
        bf16x8 pk_;                                                            \
        _Pragma("unroll")                                                      \
        for (int i_ = 0; i_ < 4; ++i_) {                                       \
            pk_[i_]     = (__bf16)u_[i_];                                      \
            pk_[4 + i_] = (__bf16)v_[i_];                                      \
        }                                                                      \
        *(bf16x8*)((char*)sm + (slot) * 65536 + (boff) + (hh) * 16384          \
                   + l_ * 8192 + dlane) = pk_;                                 \
    }                                                                          \
} while (0)

#define READ_A(slot, mh) do {                                                  \
    _Pragma("unroll")                                                          \
    for (int mi_ = 0; mi_ < 4; ++mi_) {                                        \
        int r_ = wm * 128 + (mh) * 64 + mi_ * 16 + arow;                       \
        const char* p_ = smc + (slot) * 65536 + r_ * 128;                      \
        int s_ = (r_ & 7) << 4;                                                \
        af[mi_][0] = *(const bf16x8*)(p_ + (kq16 ^ s_));                       \
        af[mi_][1] = *(const bf16x8*)(p_ + ((64 + kq16) ^ s_));                \
    }                                                                          \
} while (0)

#define READ_B(slot, nh) do {                                                  \
    _Pragma("unroll")                                                          \
    for (int ni_ = 0; ni_ < 2; ++ni_) {                                        \
        int r_ = wn * 64 + (nh) * 32 + ni_ * 16 + arow;                        \
        const char* p_ = smc + (slot) * 65536 + 32768 + r_ * 128;              \
        int s_ = (r_ & 7) << 4;                                                \
        bB[ni_][0] = *(const bf16x8*)(p_ + (kq16 ^ s_));                       \
        bB[ni_][1] = *(const bf16x8*)(p_ + ((64 + kq16) ^ s_));                \
    }                                                                          \
} while (0)

#define MFMA_Q(mh, nh) do {                                                    \
    __builtin_amdgcn_s_setprio(1);                                             \
    _Pragma("unroll")                                                          \
    for (int kk_ = 0; kk_ < 2; ++kk_)                                          \
        _Pragma("unroll")                                                      \
        for (int mi_ = 0; mi_ < 4; ++mi_)                                      \
            _Pragma("unroll")                                                  \
            for (int ni_ = 0; ni_ < 2; ++ni_)                                  \
                acc[(mh) * 4 + mi_][(nh) * 2 + ni_] =                          \
                    __builtin_amdgcn_mfma_f32_16x16x32_bf16(                   \
                        af[mi_][kk_], bB[ni_][kk_],                            \
                        acc[(mh) * 4 + mi_][(nh) * 2 + ni_], 0, 0, 0);         \
    __builtin_amdgcn_s_setprio(0);                                             \
} while (0)

#define PBAR() do {                                                            \
    __builtin_amdgcn_s_barrier();                                              \
    __builtin_amdgcn_sched_barrier(0);                                         \
    asm volatile("" ::: "memory");                                             \
} while (0)
#define LGKMDRAIN() asm volatile("s_waitcnt lgkmcnt(0)" ::: "memory")

    bf16x8 af[4][2];              // A-half frags (cached 2 phases)
    bf16x8 bB[2][2];              // B-quarter frags (re-read each phase)

    // prologue: stage tile 0 fully via the same chunk ping-pong; prime c0
    // with tile 1's A-hh0; drain; barrier.
    ISSUE(c0, X, baseA, 0, 0);
    ISSUE(c1, X, baseA, 1, 0);
    WRITE(c0, qA, 0, 0, 0);
    ISSUE(c0, Pr, baseB, 0, 0);
    WRITE(c1, qA, 1, 0, 0);
    ISSUE(c1, Pr, baseB, 1, 0);
    WRITE(c0, qB, 0, 0, 32768);
    WRITE(c1, qB, 1, 0, 32768);
    if (NKT > 1) ISSUE(c0, X, baseA, 0, 1);
    LGKMDRAIN();
    PBAR();

    for (int kt = 0; kt < NKT; ++kt) {
        const int slot = kt & 1;
        const int nslot = slot ^ 1;
        const bool more = (kt + 1) < NKT;
        const bool more2 = (kt + 2) < NKT;

        // ph1: write c0 (A.hh0, next tile) + issue c1 (A.hh1); Q00
        if (more) { WRITE(c0, qA, 0, nslot, 0); ISSUE(c1, X, baseA, 1, kt + 1); }
        READ_A(slot, 0); READ_B(slot, 0);
        MFMA_Q(0, 0); PBAR();
        // ph2: write c1 (A.hh1) + issue c0 (B.hh0); Q01
        if (more) { WRITE(c1, qA, 1, nslot, 0); ISSUE(c0, Pr, baseB, 0, kt + 1); }
        READ_B(slot, 1);
        MFMA_Q(0, 1); PBAR();
        // ph3: write c0 (B.hh0) + issue c1 (B.hh1); Q10
        if (more) { WRITE(c0, qB, 0, nslot, 32768); ISSUE(c1, Pr, baseB, 1, kt + 1); }
        READ_A(slot, 1); READ_B(slot, 0);
        MFMA_Q(1, 0); PBAR();
        // ph4: write c1 (B.hh1) + prime c0 (A.hh0 of kt+2); Q11; drain; publish
        if (more) WRITE(c1, qB, 1, nslot, 32768);
        if (more2) ISSUE(c0, X, baseA, 0, kt + 2);
        READ_B(slot, 1);
        MFMA_Q(1, 1);
        LGKMDRAIN();
        PBAR();
    }

#undef ISSUE
#undef WRITE
#undef READ_A
#undef READ_B
#undef MFMA_Q
#undef PBAR
#undef LGKMDRAIN

    // ---- reduce per-thread sum-of-squares into sqx/sqp (local rows) ----
    // Each 8-lane group (same lane>>3) covers all 8 col16 slices of one row.
#pragma unroll
    for (int hh = 0; hh < 2; ++hh)
#pragma unroll
        for (int l = 0; l < 2; ++l) {
            float a = qA[hh][l], b = qB[hh][l];
#pragma unroll
            for (int m = 1; m <= 4; m <<= 1) {
                a += __shfl_xor(a, m);
                b += __shfl_xor(b, m);
            }
            if ((lane & 7) == 0) {
                int r = hh * 128 + l * 64 + wid * 8 + rsub;
                sqx[r] = a;
                sqp[r] = b;
            }
        }

    // epilogue: score = d^2 / (xsq + psq - 2d + eps), staged through LDS so
    // global stores are full 1KB-per-wave dwordx4 rows. Two passes of 128
    // rows (wm half each). Swizzle: logical (row,col) at physical
    // col ^ (((row>>2)&1)<<4); reader loads physical (lane*4)^swz (logical
    // cols [lane*4,+3]) and stores to bcol + lane*4.
    float* smf = (float*)sm;
#pragma unroll
    for (int pass = 0; pass < 2; ++pass) {
        __syncthreads();
        if (wm == pass) {
#pragma unroll
            for (int ni = 0; ni < 4; ++ni) {
                int lcc = wn * 64 + ni * 16 + arow;
                float ps = sqp[lcc];
#pragma unroll
                for (int mi = 0; mi < 8; ++mi) {
                    f32x4 c = acc[mi][ni];
                    int lr0 = mi * 16 + (lane >> 4) * 4;   // local row, mult of 4
                    f32x4 xs4 = *(const f32x4*)(&sqx[pass * 128 + lr0]);
                    int lcs = lcc ^ (((lr0 >> 2) & 1) << 4);
#pragma unroll
                    for (int j = 0; j < 4; ++j) {
                        float dv = c[j];
                        float denom = xs4[j] + ps - 2.0f * dv + EPS;
                        smf[(lr0 + j) * 256 + lcs] = dv * dv / denom;
                    }
                }
            }
        }
        __syncthreads();
#pragma unroll
        for (int rr = 0; rr < 16; ++rr) {
            int r = wid * 16 + rr;
            int swz = ((r >> 2) & 1) << 4;
            int c0l = lane * 4;                             // logical col
            f32x4 v = *(const f32x4*)(smf + r * 256 + (c0l ^ swz));
            *(f32x4*)(out + (size_t)(brow + pass * 128 + r) * N + bcol + c0l) = v;
        }
    }
}

__global__ void yat_fallback(const float* __restrict__ x, const float* __restrict__ p,
                             float* __restrict__ out, int B, int P, int D) {
    __shared__ float xs[1024];
    int b = blockIdx.x;
    int pc = blockIdx.y * 256 + threadIdx.x;
    for (int i = threadIdx.x; i < D; i += 256) xs[i] = x[(size_t)b * D + i];
    __syncthreads();
    if (pc >= P) return;
    float dot = 0.f, psq = 0.f, xsq = 0.f;
    for (int k = 0; k < D; ++k) {
        float pv = p[(size_t)pc * D + k];
        float xv = xs[k];
        dot += xv * pv;
        psq += pv * pv;
        xsq += xv * xv;
    }
    float denom = xsq + psq - 2.f * dot + EPS;
    out[(size_t)b * P + pc] = dot * dot / denom;
}

extern "C" void kernel_launch(void* const* d_in, const int* in_sizes, int n_in,
                              void* d_out, int out_size, void* d_ws, size_t ws_size,
                              hipStream_t stream) {
    const float* x = (const float*)d_in[0];
    const float* p = (const float*)d_in[1];
    float* out = (float*)d_out;

    const int D = 1024;
    const int B = in_sizes[0] / D;
    const int P = in_sizes[1] / D;

    int nblocks = (B / 256) * (P / 256);
    if ((B % 256) || (P % 256) || (D % 64) || (nblocks % 8)) {
        yat_fallback<<<dim3(B, (P + 255) / 256), 256, 0, stream>>>(x, p, out, B, P, D);
        return;
    }

    yat_fused<<<dim3(nblocks), 512, 0, stream>>>(x, p, out, B, P, D);
}